// Round 12
// baseline (83.169 us; speedup 1.0000x reference)
//
#include <hip/hip_runtime.h>
#include <math.h>

#define BB   64
#define CC   64
#define HH   112
#define WW   112
#define HIDN 256
#define PLANE   (HH * WW)      // 12544
#define PLANE4  (PLANE / 4)    // 3136 float4 per plane
#define BODY4   3072           // 12 * 256
#define ROW4    (WW / 4)       // 28

typedef float fvec4 __attribute__((ext_vector_type(4)));

// ---------------- Kernel 1: global average pool per (b,c) plane ----------------
// NT (evict-first) loads: pool is read-pipe capped either way; keep L3 free.
__global__ __launch_bounds__(256) void pool_kernel(const float* __restrict__ x,
                                                   float* __restrict__ xfeat) {
    int plane = blockIdx.x;  // b*CC + c
    const fvec4* p = (const fvec4*)(x + (size_t)plane * PLANE);
    int t = threadIdx.x;
    float s0 = 0.f, s1 = 0.f, s2 = 0.f, s3 = 0.f;
    #pragma unroll
    for (int i = t; i < BODY4; i += 256) {       // 12 iterations, independent loads
        fvec4 v = __builtin_nontemporal_load(&p[i]);
        s0 += v.x; s1 += v.y; s2 += v.z; s3 += v.w;
    }
    if (t < PLANE4 - BODY4) {                    // 64-thread tail
        fvec4 v = __builtin_nontemporal_load(&p[BODY4 + t]);
        s0 += v.x; s1 += v.y; s2 += v.z; s3 += v.w;
    }
    float s = (s0 + s1) + (s2 + s3);
    for (int off = 32; off > 0; off >>= 1) s += __shfl_down(s, off, 64);
    __shared__ float red[4];
    int lane = t & 63, wid = t >> 6;
    if (lane == 0) red[wid] = s;
    __syncthreads();
    if (t == 0) {
        float tt = (red[0] + red[1]) + (red[2] + red[3]);
        xfeat[plane] = tt / (float)PLANE;
    }
}

// ---------------- Kernel 2: projection + BN1 + ReLU + PLIF + projection +
//                  9 border-class conv/BN2/ReLU/tanh values per (b,c) ----------
__global__ __launch_bounds__(256) void plif_kernel(
        const float* __restrict__ xfeat,
        const float* __restrict__ w_in,
        const float* __restrict__ bn1_gamma, const float* __restrict__ bn1_beta,
        const float* __restrict__ bn1_mean,  const float* __restrict__ bn1_var,
        const float* __restrict__ decay_param, const float* __restrict__ v_th,
        const float* __restrict__ w_out, const float* __restrict__ conv_w,
        const float* __restrict__ bn2_gamma, const float* __restrict__ bn2_beta,
        const float* __restrict__ bn2_mean,  const float* __restrict__ bn2_var,
        const float* __restrict__ scale,
        float* __restrict__ vals) {
    int b = blockIdx.x;          // sample
    int h = threadIdx.x;         // hidden unit (0..255)
    __shared__ float  xf[CC];
    __shared__ double red[4];
    __shared__ float  sbin[HIDN];
    __shared__ double bmred[CC][4];
    __shared__ double modv[CC];

    if (h < CC) xf[h] = xfeat[b * CC + h];
    __syncthreads();

    // h_vec = x_feat @ w_in.T  (w_in is (HID, C) row-major); keep serial order
    double hv = 0.0;
    #pragma unroll 8
    for (int c = 0; c < CC; ++c)
        hv += (double)xf[c] * (double)w_in[h * CC + c];

    // BN1 (eval) + ReLU
    hv = (hv - (double)bn1_mean[h]) / sqrt((double)bn1_var[h] + 1e-5)
             * (double)bn1_gamma[h] + (double)bn1_beta[h];
    if (hv < 0.0) hv = 0.0;

    double d   = 1.0 / (1.0 + exp(-(double)decay_param[0]));
    double vth = (double)v_th[0];

    // PLIF recurrence, T = 4 (order-identical to the absmax-passing version)
    double mem_s = 0.0, sp_s = 0.0, spike = 0.0;
    int lane = h & 63, wid = h >> 6;
    for (int t = 0; t < 4; ++t) {
        double mem = d * (mem_s - vth * sp_s) + hv;
        double a = fabs(mem);
        for (int off = 32; off > 0; off >>= 1) a += __shfl_down(a, off, 64);
        if (lane == 0) red[wid] = a;
        __syncthreads();
        double denom = ((red[0] + red[1]) + (red[2] + red[3])) / (double)HIDN + 1e-6;
        __syncthreads();
        mem = mem / denom;
        spike = (mem >= vth) ? 1.0 : 0.0;
        mem_s = mem;
        sp_s  = spike;
    }

    sbin[h] = (float)(2.0 * spike - 1.0);   // exactly +-1
    __syncthreads();

    // binary @ w_out.T with all 256 threads: channel = h&63, quarter = h>>6
    {
        int c = h & 63, part = h >> 6;
        const float* wr = w_out + c * HIDN + part * 64;
        const float* sb = sbin + part * 64;
        double bm = 0.0;
        #pragma unroll 8
        for (int k = 0; k < 64; ++k)
            bm += (double)sb[k] * (double)wr[k];
        bmred[c][part] = bm;
    }
    __syncthreads();
    if (h < CC) {
        double t = ((bmred[h][0] + bmred[h][1]) + bmred[h][2]) + bmred[h][3];
        modv[h] = 1.0 + tanh((double)scale[h] * t) * 0.5;
    }
    __syncthreads();

    // 9 border classes x 64 channels = 576 tasks over 256 threads
    for (int task = h; task < CC * 9; task += 256) {
        int c  = task / 9;
        int cl = task - c * 9;
        int rc = cl / 3, cc2 = cl - rc * 3;
        int kh0 = (rc == 0) ? 1 : 0, kh1 = (rc == 2) ? 1 : 2;
        int kw0 = (cc2 == 0) ? 1 : 0, kw1 = (cc2 == 2) ? 1 : 2;
        double S = 0.0;
        for (int kh = kh0; kh <= kh1; ++kh)
            for (int kw = kw0; kw <= kw1; ++kw)
                S += (double)conv_w[c * 9 + kh * 3 + kw];
        double y = modv[c] * S;                                      // conv of const plane
        y = (y - (double)bn2_mean[c]) / sqrt((double)bn2_var[c] + 1e-5)
                * (double)bn2_gamma[c] + (double)bn2_beta[c];        // BN2 (eval)
        if (y < 0.0) y = 0.0;                                        // ReLU
        vals[(b * CC + c) * 9 + cl] = (float)(1.0 + 0.25 * tanh(y));
    }
}

// ---- nt + sc0 sc1 store: write-through AND evict-first — hypothesis: L3 drops
// the line instead of maintaining it -> pure HBM write stream at memset rate. --
__device__ __forceinline__ void store_wt(const fvec4 v, fvec4* addr) {
    asm volatile("global_store_dwordx4 %0, %1, off nt sc0 sc1"
                 :: "v"(addr), "v"(v) : "memory");
}

// ---- Kernel 3: fill with hoisted per-thread constant store values ------------
__global__ __launch_bounds__(256) void fill_kernel(const float* __restrict__ vals,
                                                   float* __restrict__ out) {
    int plane = blockIdx.x;  // b*CC + c
    __shared__ float v[9];
    int t = threadIdx.x;
    if (t < 9) v[t] = vals[plane * 9 + t];
    __syncthreads();
    fvec4* o4 = (fvec4*)(out + (size_t)plane * PLANE);

    // top (row 0) and bottom (row 111): 56 one-shot stores
    if (t < 56) {
        int top  = (t < 28);
        int q    = top ? t : t - 28;
        int base = top ? 0 : 6;
        float m  = v[base + 1];
        fvec4 val = { (q == 0) ? v[base] : m, m, m,
                      (q == ROW4 - 1) ? v[base + 2] : m };
        store_wt(val, &o4[(top ? 0 : (HH - 1)) * ROW4 + q]);
    }

    // middle rows 1..110: fixed column q per thread, stride-9 row walk
    if (t < 252) {
        int q = t % ROW4;            // 0..27, constant per thread
        int g = t / ROW4;            // 0..8
        float m = v[4];
        fvec4 val = { (q == 0) ? v[3] : m, m, m,
                      (q == ROW4 - 1) ? v[5] : m };
        #pragma unroll 4
        for (int r = 1 + g; r < HH - 1; r += 9)    // 12-13 iterations
            store_wt(val, &o4[r * ROW4 + q]);
    }
}

extern "C" void kernel_launch(void* const* d_in, const int* in_sizes, int n_in,
                              void* d_out, int out_size, void* d_ws, size_t ws_size,
                              hipStream_t stream) {
    const float* x          = (const float*)d_in[0];
    const float* w_in       = (const float*)d_in[1];
    const float* bn1_gamma  = (const float*)d_in[2];
    const float* bn1_beta   = (const float*)d_in[3];
    const float* bn1_mean   = (const float*)d_in[4];
    const float* bn1_var    = (const float*)d_in[5];
    const float* decay_p    = (const float*)d_in[6];
    const float* v_th       = (const float*)d_in[7];
    const float* w_out      = (const float*)d_in[8];
    const float* conv_w     = (const float*)d_in[9];
    const float* bn2_gamma  = (const float*)d_in[10];
    const float* bn2_beta   = (const float*)d_in[11];
    const float* bn2_mean   = (const float*)d_in[12];
    const float* bn2_var    = (const float*)d_in[13];
    const float* scale      = (const float*)d_in[14];
    float* out = (float*)d_out;

    float* xfeat = (float*)d_ws;            // 4096 floats
    float* vals  = xfeat + BB * CC;         // 4096*9 floats

    pool_kernel<<<BB * CC, 256, 0, stream>>>(x, xfeat);
    plif_kernel<<<BB, 256, 0, stream>>>(xfeat, w_in, bn1_gamma, bn1_beta,
                                        bn1_mean, bn1_var, decay_p, v_th,
                                        w_out, conv_w, bn2_gamma, bn2_beta,
                                        bn2_mean, bn2_var, scale, vals);
    fill_kernel<<<BB * CC, 256, 0, stream>>>(vals, out);
}

// Round 13
// 75.835 us; speedup vs baseline: 1.0967x; 1.0967x over previous
//
#include <hip/hip_runtime.h>
#include <math.h>

#define BB   64
#define CC   64
#define HH   112
#define WW   112
#define HIDN 256
#define PLANE   (HH * WW)      // 12544
#define PLANE4  (PLANE / 4)    // 3136 float4 per plane
#define BODY4   3072           // 12 * 256
#define ROW4    (WW / 4)       // 28

typedef float fvec4 __attribute__((ext_vector_type(4)));

// ---------------- Kernel 1: global average pool per (b,c) plane ----------------
// NT (evict-first) loads: pool is read-pipe capped either way; keep L3 free.
__global__ __launch_bounds__(256) void pool_kernel(const float* __restrict__ x,
                                                   float* __restrict__ xfeat) {
    int plane = blockIdx.x;  // b*CC + c
    const fvec4* p = (const fvec4*)(x + (size_t)plane * PLANE);
    int t = threadIdx.x;
    float s0 = 0.f, s1 = 0.f, s2 = 0.f, s3 = 0.f;
    #pragma unroll
    for (int i = t; i < BODY4; i += 256) {       // 12 iterations, independent loads
        fvec4 v = __builtin_nontemporal_load(&p[i]);
        s0 += v.x; s1 += v.y; s2 += v.z; s3 += v.w;
    }
    if (t < PLANE4 - BODY4) {                    // 64-thread tail
        fvec4 v = __builtin_nontemporal_load(&p[BODY4 + t]);
        s0 += v.x; s1 += v.y; s2 += v.z; s3 += v.w;
    }
    float s = (s0 + s1) + (s2 + s3);
    for (int off = 32; off > 0; off >>= 1) s += __shfl_down(s, off, 64);
    __shared__ float red[4];
    int lane = t & 63, wid = t >> 6;
    if (lane == 0) red[wid] = s;
    __syncthreads();
    if (t == 0) {
        float tt = (red[0] + red[1]) + (red[2] + red[3]);
        xfeat[plane] = tt / (float)PLANE;
    }
}

// ---------------- Kernel 2: projection + BN1 + ReLU + PLIF + projection +
//                  9 border-class conv/BN2/ReLU/tanh values per (b,c) ----------
__global__ __launch_bounds__(256) void plif_kernel(
        const float* __restrict__ xfeat,
        const float* __restrict__ w_in,
        const float* __restrict__ bn1_gamma, const float* __restrict__ bn1_beta,
        const float* __restrict__ bn1_mean,  const float* __restrict__ bn1_var,
        const float* __restrict__ decay_param, const float* __restrict__ v_th,
        const float* __restrict__ w_out, const float* __restrict__ conv_w,
        const float* __restrict__ bn2_gamma, const float* __restrict__ bn2_beta,
        const float* __restrict__ bn2_mean,  const float* __restrict__ bn2_var,
        const float* __restrict__ scale,
        float* __restrict__ vals) {
    int b = blockIdx.x;          // sample
    int h = threadIdx.x;         // hidden unit (0..255)
    __shared__ float  xf[CC];
    __shared__ double red[4];
    __shared__ float  sbin[HIDN];
    __shared__ double bmred[CC][4];
    __shared__ double modv[CC];

    if (h < CC) xf[h] = xfeat[b * CC + h];
    __syncthreads();

    // h_vec = x_feat @ w_in.T  (w_in is (HID, C) row-major); keep serial order
    double hv = 0.0;
    #pragma unroll 8
    for (int c = 0; c < CC; ++c)
        hv += (double)xf[c] * (double)w_in[h * CC + c];

    // BN1 (eval) + ReLU
    hv = (hv - (double)bn1_mean[h]) / sqrt((double)bn1_var[h] + 1e-5)
             * (double)bn1_gamma[h] + (double)bn1_beta[h];
    if (hv < 0.0) hv = 0.0;

    double d   = 1.0 / (1.0 + exp(-(double)decay_param[0]));
    double vth = (double)v_th[0];

    // PLIF recurrence, T = 4 (order-identical to the absmax-passing version)
    double mem_s = 0.0, sp_s = 0.0, spike = 0.0;
    int lane = h & 63, wid = h >> 6;
    for (int t = 0; t < 4; ++t) {
        double mem = d * (mem_s - vth * sp_s) + hv;
        double a = fabs(mem);
        for (int off = 32; off > 0; off >>= 1) a += __shfl_down(a, off, 64);
        if (lane == 0) red[wid] = a;
        __syncthreads();
        double denom = ((red[0] + red[1]) + (red[2] + red[3])) / (double)HIDN + 1e-6;
        __syncthreads();
        mem = mem / denom;
        spike = (mem >= vth) ? 1.0 : 0.0;
        mem_s = mem;
        sp_s  = spike;
    }

    sbin[h] = (float)(2.0 * spike - 1.0);   // exactly +-1
    __syncthreads();

    // binary @ w_out.T with all 256 threads: channel = h&63, quarter = h>>6
    {
        int c = h & 63, part = h >> 6;
        const float* wr = w_out + c * HIDN + part * 64;
        const float* sb = sbin + part * 64;
        double bm = 0.0;
        #pragma unroll 8
        for (int k = 0; k < 64; ++k)
            bm += (double)sb[k] * (double)wr[k];
        bmred[c][part] = bm;
    }
    __syncthreads();
    if (h < CC) {
        double t = ((bmred[h][0] + bmred[h][1]) + bmred[h][2]) + bmred[h][3];
        modv[h] = 1.0 + tanh((double)scale[h] * t) * 0.5;
    }
    __syncthreads();

    // 9 border classes x 64 channels = 576 tasks over 256 threads
    for (int task = h; task < CC * 9; task += 256) {
        int c  = task / 9;
        int cl = task - c * 9;
        int rc = cl / 3, cc2 = cl - rc * 3;
        int kh0 = (rc == 0) ? 1 : 0, kh1 = (rc == 2) ? 1 : 2;
        int kw0 = (cc2 == 0) ? 1 : 0, kw1 = (cc2 == 2) ? 1 : 2;
        double S = 0.0;
        for (int kh = kh0; kh <= kh1; ++kh)
            for (int kw = kw0; kw <= kw1; ++kw)
                S += (double)conv_w[c * 9 + kh * 3 + kw];
        double y = modv[c] * S;                                      // conv of const plane
        y = (y - (double)bn2_mean[c]) / sqrt((double)bn2_var[c] + 1e-5)
                * (double)bn2_gamma[c] + (double)bn2_beta[c];        // BN2 (eval)
        if (y < 0.0) y = 0.0;                                        // ReLU
        vals[(b * CC + c) * 9 + cl] = (float)(1.0 + 0.25 * tanh(y));
    }
}

// ---- sc0 sc1 write-through store (best of 4 flavors measured: plain 41-43us,
// nt 48us, sc0 sc1 38us, nt+sc0+sc1 45us for the 205MB fill) -------------------
__device__ __forceinline__ void store_wt(const fvec4 v, fvec4* addr) {
    asm volatile("global_store_dwordx4 %0, %1, off sc0 sc1"
                 :: "v"(addr), "v"(v) : "memory");
}

// ---- Kernel 3: fill with hoisted per-thread constant store values ------------
__global__ __launch_bounds__(256) void fill_kernel(const float* __restrict__ vals,
                                                   float* __restrict__ out) {
    int plane = blockIdx.x;  // b*CC + c
    __shared__ float v[9];
    int t = threadIdx.x;
    if (t < 9) v[t] = vals[plane * 9 + t];
    __syncthreads();
    fvec4* o4 = (fvec4*)(out + (size_t)plane * PLANE);

    // top (row 0) and bottom (row 111): 56 one-shot stores
    if (t < 56) {
        int top  = (t < 28);
        int q    = top ? t : t - 28;
        int base = top ? 0 : 6;
        float m  = v[base + 1];
        fvec4 val = { (q == 0) ? v[base] : m, m, m,
                      (q == ROW4 - 1) ? v[base + 2] : m };
        store_wt(val, &o4[(top ? 0 : (HH - 1)) * ROW4 + q]);
    }

    // middle rows 1..110: fixed column q per thread, stride-9 row walk
    if (t < 252) {
        int q = t % ROW4;            // 0..27, constant per thread
        int g = t / ROW4;            // 0..8
        float m = v[4];
        fvec4 val = { (q == 0) ? v[3] : m, m, m,
                      (q == ROW4 - 1) ? v[5] : m };
        #pragma unroll 4
        for (int r = 1 + g; r < HH - 1; r += 9)    // 12-13 iterations
            store_wt(val, &o4[r * ROW4 + q]);
    }
}

extern "C" void kernel_launch(void* const* d_in, const int* in_sizes, int n_in,
                              void* d_out, int out_size, void* d_ws, size_t ws_size,
                              hipStream_t stream) {
    const float* x          = (const float*)d_in[0];
    const float* w_in       = (const float*)d_in[1];
    const float* bn1_gamma  = (const float*)d_in[2];
    const float* bn1_beta   = (const float*)d_in[3];
    const float* bn1_mean   = (const float*)d_in[4];
    const float* bn1_var    = (const float*)d_in[5];
    const float* decay_p    = (const float*)d_in[6];
    const float* v_th       = (const float*)d_in[7];
    const float* w_out      = (const float*)d_in[8];
    const float* conv_w     = (const float*)d_in[9];
    const float* bn2_gamma  = (const float*)d_in[10];
    const float* bn2_beta   = (const float*)d_in[11];
    const float* bn2_mean   = (const float*)d_in[12];
    const float* bn2_var    = (const float*)d_in[13];
    const float* scale      = (const float*)d_in[14];
    float* out = (float*)d_out;

    float* xfeat = (float*)d_ws;            // 4096 floats
    float* vals  = xfeat + BB * CC;         // 4096*9 floats

    pool_kernel<<<BB * CC, 256, 0, stream>>>(x, xfeat);
    plif_kernel<<<BB, 256, 0, stream>>>(xfeat, w_in, bn1_gamma, bn1_beta,
                                        bn1_mean, bn1_var, decay_p, v_th,
                                        w_out, conv_w, bn2_gamma, bn2_beta,
                                        bn2_mean, bn2_var, scale, vals);
    fill_kernel<<<BB * CC, 256, 0, stream>>>(vals, out);
}